// Round 17
// baseline (190.078 us; speedup 1.0000x reference)
//
#include <hip/hip_runtime.h>
#include <hip/hip_bf16.h>

// Problem constants
#define NLOC 512
#define NALL 640
#define NNEI 96
#define ASEL 20
#define NDIM 128
#define EDIM 64
#define ADIM 64

typedef short bf16x8 __attribute__((ext_vector_type(8)));
typedef float f32x4 __attribute__((ext_vector_type(4)));
typedef unsigned short ushort8 __attribute__((ext_vector_type(8)));
typedef unsigned short ushort4_t __attribute__((ext_vector_type(4)));

__device__ __forceinline__ unsigned short f2bf(float f) {
    unsigned int u = __float_as_uint(f);
    unsigned int r = (u + 0x7FFFu + ((u >> 16) & 1u)) >> 16;
    return (unsigned short)r;
}
__device__ __forceinline__ float bf2f(unsigned short u) {
    return __uint_as_float(((unsigned int)u) << 16);
}
__device__ __forceinline__ float silu(float x) { return x / (1.0f + __expf(-x)); }

__device__ __forceinline__ void cvt8_store(unsigned short* dst, const float* src) {
    float4 f0 = *(const float4*)src;
    float4 f1 = *(const float4*)(src + 4);
    ushort8 v;
    v[0] = f2bf(f0.x); v[1] = f2bf(f0.y); v[2] = f2bf(f0.z); v[3] = f2bf(f0.w);
    v[4] = f2bf(f1.x); v[5] = f2bf(f1.y); v[6] = f2bf(f1.z); v[7] = f2bf(f1.w);
    *(ushort8*)dst = v;
}

// ---------------- prep: ALL bf16 N-major weight blocks ----------------
__global__ void prep_bt2(const float* __restrict__ w_ang, const float* __restrict__ w_ga1,
                         const float* __restrict__ w_edge1, const float* __restrict__ w_lin2,
                         const float* __restrict__ w_proj, const float* __restrict__ w_self,
                         unsigned short* __restrict__ bt_ae, unsigned short* __restrict__ bt_g2e,
                         unsigned short* __restrict__ bt_sm, unsigned short* __restrict__ bt_pij) {
    int idx = blockIdx.x * 256 + threadIdx.x;  // 131072 total
    if (idx < 8192) {
        int k = idx & 63, n = idx >> 6;
        bt_ae[idx] = f2bf((n < 64) ? w_ang[k * 64 + n] : w_ga1[k * 64 + (n - 64)]);
    } else if (idx < 32768) {
        int id2 = idx - 8192;
        int k = id2 & 63, n = id2 >> 6;
        float v;
        if (n < 128)      v = w_edge1[(256 + k) * 128 + n];
        else if (n < 192) v = w_lin2[(256 + k) * 64 + (n - 128)];
        else if (n < 256) v = 0.0f;
        else              v = w_proj[k * 128 + (n - 256)];
        bt_g2e[id2] = f2bf(v);
    } else if (idx < 114688) {
        int id3 = idx - 32768;
        int k = id3 & 127, n = id3 >> 7;
        float v;
        if (n < 128)      v = w_edge1[k * 128 + n];
        else if (n < 192) v = w_lin2[k * 64 + (n - 128)];
        else if (n < 320) v = w_edge1[(128 + k) * 128 + (n - 192)];
        else if (n < 384) v = w_lin2[(128 + k) * 64 + (n - 320)];
        else if (n < 512) { int c = n - 384;
            v = (c < 64) ? w_ang[(64 + k) * 64 + c] : w_ga1[(64 + k) * 64 + (c - 64)]; }
        else              v = w_self[k * 128 + (n - 512)];
        bt_sm[id3] = f2bf(v);
    } else {
        int id4 = idx - 114688;  // < 16384
        int k = id4 & 63, n = id4 >> 6;
        float v;
        if (n < 128) v = (n < 64) ? w_ang[(192 + k) * 64 + n] : w_ga1[(192 + k) * 64 + (n - 64)];
        else { int c = n - 128;
            v = (c < 64) ? w_ang[(256 + k) * 64 + c] : w_ga1[(256 + k) * 64 + (c - 64)]; }
        bt_pij[id4] = f2bf(v);
    }
}

// ---------------- gemm_small: M=640 (g1_ext), K=128, N=640 (E1|E2|P1a|g1self) ----------
__global__ __launch_bounds__(256) void gemm_small(
    const float* __restrict__ g1_ext, const unsigned short* __restrict__ bt_sm,
    const float* __restrict__ b_self, float* __restrict__ P1a, float* __restrict__ g1self,
    float* __restrict__ E1, float* __restrict__ E2) {
    const int m0 = blockIdx.x * 128;
    const int ntile = blockIdx.y;  // 0..4
    __shared__ __align__(16) unsigned short Asl[128 * 136];
    __shared__ __align__(16) unsigned short Bsl[128 * 136];
    const int tid = threadIdx.x;
#pragma unroll
    for (int u = 0; u < 8; u++) {
        int g = tid + u * 256;
        int row = g >> 4, seg = g & 15;
        cvt8_store(&Asl[row * 136 + seg * 8], g1_ext + (m0 + row) * 128 + seg * 8);
        *(ushort8*)&Bsl[row * 136 + seg * 8] =
            *(const ushort8*)&bt_sm[(ntile * 128 + row) * 128 + seg * 8];
    }
    __syncthreads();
    const int lane = tid & 63, wid = tid >> 6;
    const int wr = wid >> 1, wc = wid & 1;
    const int r15 = lane & 15, kg = lane >> 4;
    f32x4 acc[4][4] = {};
#pragma unroll
    for (int h = 0; h < 4; h++) {
        bf16x8 afr[4], bfr[4];
#pragma unroll
        for (int mi = 0; mi < 4; mi++)
            afr[mi] = *(const bf16x8*)&Asl[(wr * 64 + mi * 16 + r15) * 136 + h * 32 + kg * 8];
#pragma unroll
        for (int ni = 0; ni < 4; ni++)
            bfr[ni] = *(const bf16x8*)&Bsl[(wc * 64 + ni * 16 + r15) * 136 + h * 32 + kg * 8];
#pragma unroll
        for (int mi = 0; mi < 4; mi++)
#pragma unroll
            for (int ni = 0; ni < 4; ni++)
                acc[mi][ni] = __builtin_amdgcn_mfma_f32_16x16x32_bf16(afr[mi], bfr[ni], acc[mi][ni], 0, 0, 0);
    }
#pragma unroll
    for (int mi = 0; mi < 4; mi++) {
        int rbase = m0 + wr * 64 + mi * 16 + kg * 4;
#pragma unroll
        for (int ni = 0; ni < 4; ni++) {
            int gc = ntile * 128 + wc * 64 + ni * 16 + r15;
#pragma unroll
            for (int t2 = 0; t2 < 4; t2++) {
                int a = rbase + t2;
                float z = acc[mi][ni][t2];
                if (gc < 192) { if (a < 512) E1[a * 192 + gc] = z; }
                else if (gc < 384) E2[a * 192 + (gc - 192)] = z;
                else if (gc < 512) { if (a < 512) P1a[a * 128 + (gc - 384)] = z; }
                else { if (a < 512) g1self[a * 128 + (gc - 512)] = silu(z + b_self[gc - 512]); }
            }
        }
    }
}

// ---------------- gemm_pij: M=10240 (l,i), K=64 (g2a), N=2x128 (P_i, P_j [+P_jT]) ------
__global__ __launch_bounds__(256) void gemm_pij(
    const float* __restrict__ g2, const unsigned short* __restrict__ bt_pij,
    unsigned short* __restrict__ P_i, unsigned short* __restrict__ P_j,
    unsigned short* __restrict__ P_jT) {
    const int m0 = blockIdx.x * 128;
    const int ntile = blockIdx.y;  // 0 = P_i, 1 = P_j
    __shared__ __align__(16) unsigned short Asl[128 * 72];
    const int tid = threadIdx.x;
#pragma unroll
    for (int u = 0; u < 4; u++) {
        int g = tid + u * 256;
        int row = g >> 3, seg = g & 7;
        int li = m0 + row, l = li / 20, i = li - l * 20;
        cvt8_store(&Asl[row * 72 + seg * 8], g2 + (l * 96 + i) * 64 + seg * 8);
    }
    __syncthreads();
    const int lane = tid & 63, wid = tid >> 6;
    const int wr = wid >> 1, wc = wid & 1;
    const int r15 = lane & 15, kg = lane >> 4;
    f32x4 acc[4][4] = {};
#pragma unroll
    for (int h = 0; h < 2; h++) {
        bf16x8 afr[4], bfr[4];
#pragma unroll
        for (int mi = 0; mi < 4; mi++)
            afr[mi] = *(const bf16x8*)&Asl[(wr * 64 + mi * 16 + r15) * 72 + h * 32 + kg * 8];
#pragma unroll
        for (int ni = 0; ni < 4; ni++)
            bfr[ni] = *(const bf16x8*)&bt_pij[(ntile * 128 + wc * 64 + ni * 16 + r15) * 64 + h * 32 + kg * 8];
#pragma unroll
        for (int mi = 0; mi < 4; mi++)
#pragma unroll
            for (int ni = 0; ni < 4; ni++)
                acc[mi][ni] = __builtin_amdgcn_mfma_f32_16x16x32_bf16(afr[mi], bfr[ni], acc[mi][ni], 0, 0, 0);
    }
    unsigned short* Pout = (ntile == 0) ? P_i : P_j;
#pragma unroll
    for (int mi = 0; mi < 4; mi++) {
        int rbase = m0 + wr * 64 + mi * 16 + kg * 4;
#pragma unroll
        for (int ni = 0; ni < 4; ni++) {
            int c = wc * 64 + ni * 16 + r15;
#pragma unroll
            for (int t2 = 0; t2 < 4; t2++) {
                unsigned short v = f2bf(acc[mi][ni][t2]);
                int li = rbase + t2;
                Pout[li * 128 + c] = v;
                if (ntile == 1) {
                    int l = li / 20, j = li - l * 20;
                    P_jT[(l * 128 + c) * 20 + j] = v;
                }
            }
        }
    }
}

// ---------------- sym op + term4 = silu(sym @ w_lin1 + b_lin1) ----------------
__global__ void k_sym(const float* __restrict__ g1_ext, const float* __restrict__ g2,
                      const float* __restrict__ h2, const float* __restrict__ sw,
                      const int* __restrict__ nlist, const float* __restrict__ w_lin1,
                      const float* __restrict__ b_lin1, float* __restrict__ term4) {
    int l = blockIdx.x, t = threadIdx.x;  // 256 threads
    __shared__ float h2s[96 * 3];
    __shared__ float sws[96];
    __shared__ int nls[96];
    __shared__ float hg[3 * 192];
    __shared__ float symv[768];
    __shared__ float red[128];
    if (t < 96) { sws[t] = sw[l * 96 + t]; nls[t] = nlist[l * 96 + t]; }
    for (int p = t; p < 288; p += 256) h2s[p] = h2[l * 288 + p];
    __syncthreads();
    const float inv = 0.1020620726f;
    for (int p = t; p < 576; p += 256) {
        float acc = 0.0f;
        if (p < 192) {
            int tt = p >> 6, d = p & 63;
            for (int n = 0; n < 96; n++)
                acc += h2s[n * 3 + tt] * g2[(l * 96 + n) * 64 + d] * sws[n];
            hg[tt * 192 + d] = acc * inv;
        } else {
            int q = p - 192;
            int tt = q >> 7, d = q & 127;
            for (int n = 0; n < 96; n++)
                acc += h2s[n * 3 + tt] * g1_ext[nls[n] * 128 + d] * sws[n];
            hg[tt * 192 + 64 + d] = acc * inv;
        }
    }
    __syncthreads();
    for (int p = t; p < 768; p += 256) {
        float acc = 0.0f;
        if (p < 256) {
            int d = p >> 2, a = p & 3;
            for (int tt = 0; tt < 3; tt++) acc += hg[tt * 192 + d] * hg[tt * 192 + a];
        } else {
            int q = p - 256;
            int d = q >> 2, a = q & 3;
            for (int tt = 0; tt < 3; tt++) acc += hg[tt * 192 + 64 + d] * hg[tt * 192 + 64 + a];
        }
        symv[p] = acc;
    }
    __syncthreads();
    {
        int col = t & 127, half = t >> 7;
        float acc = 0.0f;
        int k0 = half * 384;
#pragma unroll 8
        for (int k = k0; k < k0 + 384; k++) acc += symv[k] * w_lin1[k * 128 + col];
        if (half) red[col] = acc;
        __syncthreads();
        if (!half) term4[l * 128 + col] = silu(acc + red[col] + b_lin1[col]);
    }
}

// ---------------- k_ga1: angle atomic half only. M=204800, N=64 (ga1 cols) ----------
__global__ __launch_bounds__(256) void k_ga1(
    const float* __restrict__ ae, const unsigned short* __restrict__ bt_ae,
    const float* __restrict__ P1a, const unsigned short* __restrict__ P_i,
    const unsigned short* __restrict__ P_jT, const float* __restrict__ a_sw,
    const float* __restrict__ b_ga1, float* __restrict__ g2acc) {
    const int m0 = blockIdx.x * 128;
    __shared__ __align__(16) unsigned short Asl[128 * 72];
    const int tid = threadIdx.x;
#pragma unroll
    for (int u = 0; u < 4; u++) {
        int g = tid + u * 256;
        int row = g >> 3, seg = g & 7;
        cvt8_store(&Asl[row * 72 + seg * 8], ae + (m0 + row) * 64 + seg * 8);
    }
    __syncthreads();
    const int lane = tid & 63, wid = tid >> 6;
    const int r15 = lane & 15, kg = lane >> 4;
    f32x4 accB[2][4] = {};
#pragma unroll
    for (int h = 0; h < 2; h++) {
        bf16x8 afr[2], bfrB[4];
#pragma unroll
        for (int mi = 0; mi < 2; mi++)
            afr[mi] = *(const bf16x8*)&Asl[(wid * 32 + mi * 16 + r15) * 72 + h * 32 + kg * 8];
#pragma unroll
        for (int ni = 0; ni < 4; ni++)
            bfrB[ni] = *(const bf16x8*)&bt_ae[(64 + ni * 16 + r15) * 64 + h * 32 + kg * 8];
#pragma unroll
        for (int mi = 0; mi < 2; mi++)
#pragma unroll
            for (int ni = 0; ni < 4; ni++)
                accB[mi][ni] = __builtin_amdgcn_mfma_f32_16x16x32_bf16(afr[mi], bfrB[ni], accB[mi][ni], 0, 0, 0);
    }
#pragma unroll
    for (int mi = 0; mi < 2; mi++) {
        int rbase = m0 + wid * 32 + mi * 16 + kg * 4;
        int l = rbase / 400;
        int rem = rbase - l * 400;
        int i = rem / 20;
        int j0 = rem - i * 20;
        const float* p1b = P1a + l * 128;
        const unsigned short* pib = P_i + (l * 20 + i) * 128;
        float swi = a_sw[l * 20 + i];
        f32x4 swjv = *(const f32x4*)&a_sw[l * 20 + j0];
#pragma unroll
        for (int ni = 0; ni < 4; ni++) {
            int c = 64 + ni * 16 + r15;
            int cc = c - 64;
            float base = p1b[c] + bf2f(pib[c]);
            float bb = b_ga1[cc];
            ushort4_t pjtv = *(const ushort4_t*)&P_jT[(l * 128 + c) * 20 + j0];
            float part = 0.0f;
#pragma unroll
            for (int t2 = 0; t2 < 4; t2++) {
                float z = accB[mi][ni][t2] + base + bf2f(pjtv[t2]);
                part += silu(swi * swjv[t2] * z + bb);
            }
            atomicAdd(&g2acc[(l * 20 + i) * 64 + cc], part);
        }
    }
}

// ---------------- k_anew: angle output half only. M=204800, N=64 (a_new cols) --------
__global__ __launch_bounds__(256) void k_anew(
    const float* __restrict__ ae, const unsigned short* __restrict__ bt_ae,
    const float* __restrict__ P1a, const unsigned short* __restrict__ P_i,
    const unsigned short* __restrict__ P_j, const float* __restrict__ b_ang,
    float* __restrict__ a_new_out) {
    const int m0 = blockIdx.x * 128;
    __shared__ __align__(16) unsigned short Asl[128 * 72];
    const int tid = threadIdx.x;
#pragma unroll
    for (int u = 0; u < 4; u++) {
        int g = tid + u * 256;
        int row = g >> 3, seg = g & 7;
        cvt8_store(&Asl[row * 72 + seg * 8], ae + (m0 + row) * 64 + seg * 8);
    }
    __syncthreads();
    const int lane = tid & 63, wid = tid >> 6;
    const int r15 = lane & 15, kg = lane >> 4;
    f32x4 accA[2][4] = {};
#pragma unroll
    for (int h = 0; h < 2; h++) {
        bf16x8 afr[2], bfrA[4];
#pragma unroll
        for (int mi = 0; mi < 2; mi++)
            afr[mi] = *(const bf16x8*)&Asl[(wid * 32 + mi * 16 + r15) * 72 + h * 32 + kg * 8];
#pragma unroll
        for (int ni = 0; ni < 4; ni++)
            bfrA[ni] = *(const bf16x8*)&bt_ae[(ni * 16 + r15) * 64 + h * 32 + kg * 8];
#pragma unroll
        for (int mi = 0; mi < 2; mi++)
#pragma unroll
            for (int ni = 0; ni < 4; ni++)
                accA[mi][ni] = __builtin_amdgcn_mfma_f32_16x16x32_bf16(bfrA[ni], afr[mi], accA[mi][ni], 0, 0, 0);
    }
#pragma unroll
    for (int mi = 0; mi < 2; mi++) {
        int r = m0 + wid * 32 + mi * 16 + r15;
        int l = r / 400;
        int rem = r - l * 400;
        int i = rem / 20;
        int j = rem - i * 20;
        const float* p1b = P1a + l * 128;
        const unsigned short* pib = P_i + (l * 20 + i) * 128;
        const unsigned short* pjb = P_j + (l * 20 + j) * 128;
        int lr = r - m0;
#pragma unroll
        for (int ni = 0; ni < 4; ni++) {
            int n0 = ni * 16 + kg * 4;
            f32x4 p1v = *(const f32x4*)&p1b[n0];
            ushort4_t piv = *(const ushort4_t*)&pib[n0];
            ushort4_t pjv = *(const ushort4_t*)&pjb[n0];
            ushort4_t aev = *(const ushort4_t*)&Asl[lr * 72 + n0];
            f32x4 bbv = *(const f32x4*)&b_ang[n0];
            f32x4 outv;
#pragma unroll
            for (int t2 = 0; t2 < 4; t2++) {
                float z = accA[mi][ni][t2] + p1v[t2] + bf2f(piv[t2]) + bf2f(pjv[t2]);
                outv[t2] = (bf2f(aev[t2]) + silu(z + bbv[t2])) * 0.70710678f;
            }
            *(f32x4*)&a_new_out[r * 64 + n0] = outv;
        }
    }
}

// ---------------- F2: yga2 = silu((g2acc/20) @ w_ga2 + b_ga2) ----------------
__global__ void k_f2(const float* __restrict__ g2ang_acc, const float* __restrict__ w_ga2,
                     const float* __restrict__ b_ga2, float* __restrict__ yga2) {
    int l = blockIdx.x, t = threadIdx.x;
    __shared__ float gs[20 * 64];
    for (int p = t; p < 1280; p += 256) gs[p] = g2ang_acc[l * 1280 + p] * 0.05f;
    __syncthreads();
    for (int p = t; p < 1280; p += 256) {
        int i = p >> 6, c = p & 63;
        float acc = b_ga2[c];
#pragma unroll 8
        for (int k = 0; k < 64; k++) acc += gs[i * 64 + k] * w_ga2[k * 64 + c];
        yga2[l * 1280 + p] = silu(acc);
    }
}

// ---------------- edge main GEMM: M=49152, K=64; ntile 1 uses uniform waves ----------
__global__ __launch_bounds__(256) void edge_main(
    const float* __restrict__ g1_ext, const float* __restrict__ g2, const float* __restrict__ sw,
    const int* __restrict__ nlist, const unsigned short* __restrict__ bt_g2e,
    const float* __restrict__ E1, const float* __restrict__ E2,
    const float* __restrict__ b_edge1, const float* __restrict__ b_lin2,
    const float* __restrict__ b_ga2, const float* __restrict__ yga2,
    float* __restrict__ g1_acc3, float* __restrict__ g1_acc5, float* __restrict__ g2_new_out) {
    const int m0 = blockIdx.x * 128;
    const int ntile = blockIdx.y;
    __shared__ __align__(16) unsigned short Asl[128 * 72];
    const int tid = threadIdx.x;
#pragma unroll
    for (int u = 0; u < 4; u++) {
        int g = tid + u * 256;
        int row = g >> 3, seg = g & 7;
        cvt8_store(&Asl[row * 72 + seg * 8], g2 + (m0 + row) * 64 + seg * 8);
    }
    __syncthreads();
    const int lane = tid & 63, wid = tid >> 6;
    const int r15 = lane & 15, kg = lane >> 4;
    if (ntile == 1) {
        f32x4 acc[2][4] = {};
#pragma unroll
        for (int h = 0; h < 2; h++) {
            bf16x8 afr[2], bfr[4];
#pragma unroll
            for (int mi = 0; mi < 2; mi++)
                afr[mi] = *(const bf16x8*)&Asl[(wid * 32 + mi * 16 + r15) * 72 + h * 32 + kg * 8];
#pragma unroll
            for (int ni = 0; ni < 4; ni++)
                bfr[ni] = *(const bf16x8*)&bt_g2e[(128 + ni * 16 + r15) * 64 + h * 32 + kg * 8];
#pragma unroll
            for (int mi = 0; mi < 2; mi++)
#pragma unroll
                for (int ni = 0; ni < 4; ni++)
                    acc[mi][ni] = __builtin_amdgcn_mfma_f32_16x16x32_bf16(bfr[ni], afr[mi], acc[mi][ni], 0, 0, 0);
        }
#pragma unroll
        for (int mi = 0; mi < 2; mi++) {
            int r = m0 + wid * 32 + mi * 16 + r15;
            int l = r / 96;
            int nn = r - l * 96;
            const float* e1 = E1 + l * 192 + 128;
            const float* e2 = E2 + nlist[r] * 192 + 128;
            bool hasyg = (nn < ASEL);
            const float* yg = yga2 + (l * 20 + nn) * 64;
            int lr = r - m0;
#pragma unroll
            for (int ni = 0; ni < 4; ni++) {
                int n0 = ni * 16 + kg * 4;
                f32x4 e1v = *(const f32x4*)&e1[n0];
                f32x4 e2v = *(const f32x4*)&e2[n0];
                f32x4 bbv = *(const f32x4*)&b_lin2[n0];
                f32x4 bg2 = *(const f32x4*)&b_ga2[n0];
                ushort4_t g2v = *(const ushort4_t*)&Asl[lr * 72 + n0];
                f32x4 outv;
#pragma unroll
                for (int t2 = 0; t2 < 4; t2++) {
                    float z = acc[mi][ni][t2] + e1v[t2] + e2v[t2];
                    float y = silu(z + bbv[t2]);
                    float ygv = hasyg ? yg[n0 + t2] : silu(bg2[t2]);
                    outv[t2] = (bf2f(g2v[t2]) + y + ygv) * 0.57735027f;
                }
                *(f32x4*)&g2_new_out[r * 64 + n0] = outv;
            }
        }
    } else {
        const int wr = wid >> 1, wc = wid & 1;
        f32x4 acc[4][4] = {};
#pragma unroll
        for (int h = 0; h < 2; h++) {
            bf16x8 afr[4], bfr[4];
#pragma unroll
            for (int mi = 0; mi < 4; mi++)
                afr[mi] = *(const bf16x8*)&Asl[(wr * 64 + mi * 16 + r15) * 72 + h * 32 + kg * 8];
#pragma unroll
            for (int ni = 0; ni < 4; ni++)
                bfr[ni] = *(const bf16x8*)&bt_g2e[(ntile * 128 + wc * 64 + ni * 16 + r15) * 64 + h * 32 + kg * 8];
#pragma unroll
            for (int mi = 0; mi < 4; mi++)
#pragma unroll
                for (int ni = 0; ni < 4; ni++)
                    acc[mi][ni] = __builtin_amdgcn_mfma_f32_16x16x32_bf16(afr[mi], bfr[ni], acc[mi][ni], 0, 0, 0);
        }
#pragma unroll
        for (int mi = 0; mi < 4; mi++) {
            int rbase = m0 + wr * 64 + mi * 16 + kg * 4;
            int l = rbase / 96;
#pragma unroll
            for (int ni = 0; ni < 4; ni++) {
                int c = wc * 64 + ni * 16 + r15;
                if (ntile == 0) {
                    float e1 = E1[l * 192 + c];
                    float bb = b_edge1[c];
                    float part = 0.0f;
#pragma unroll
                    for (int t2 = 0; t2 < 4; t2++) {
                        int r = rbase + t2;
                        float z = acc[mi][ni][t2] + e1 + E2[nlist[r] * 192 + c];
                        part += silu(z + bb) * sw[r];
                    }
                    atomicAdd(&g1_acc5[l * 128 + c], part);
                } else {
                    float part = 0.0f;
#pragma unroll
                    for (int t2 = 0; t2 < 4; t2++) {
                        int r = rbase + t2;
                        part += acc[mi][ni][t2] * g1_ext[nlist[r] * 128 + c] * sw[r];
                    }
                    atomicAdd(&g1_acc3[l * 128 + c], part);
                }
            }
        }
    }
}

// ---------------- F1: g1_new + h2 passthrough ----------------
__global__ void k_f1(const float* __restrict__ g1_ext, const float* __restrict__ g1self,
                     const float* __restrict__ acc3, const float* __restrict__ term4,
                     const float* __restrict__ acc5, const float* __restrict__ h2,
                     float* __restrict__ out_g1, float* __restrict__ out_h2) {
    int idx = blockIdx.x * 256 + threadIdx.x;  // 65536
    float v = g1_ext[idx] + g1self[idx] + acc3[idx] * (1.0f / 96.0f) + term4[idx] +
              acc5[idx] * (1.0f / 96.0f);
    out_g1[idx] = v * 0.4472135955f;
    if (idx < 36864)  // h2: 147456 f32 = 36864 float4
        *(float4*)&out_h2[idx * 4] = *(const float4*)&h2[idx * 4];
}

extern "C" void kernel_launch(void* const* d_in, const int* in_sizes, int n_in,
                              void* d_out, int out_size, void* d_ws, size_t ws_size,
                              hipStream_t stream) {
    if (n_in < 22 || in_sizes[0] != 81920 || in_sizes[3] != 13107200) return;
    const float* g1_ext = (const float*)d_in[0];
    const float* g2     = (const float*)d_in[1];
    const float* h2     = (const float*)d_in[2];
    const float* ae     = (const float*)d_in[3];
    const float* sw     = (const float*)d_in[4];
    const float* a_sw   = (const float*)d_in[5];
    const float* w_self = (const float*)d_in[6];
    const float* b_self = (const float*)d_in[7];
    const float* w_proj = (const float*)d_in[8];
    const float* w_lin1 = (const float*)d_in[9];
    const float* b_lin1 = (const float*)d_in[10];
    const float* w_edge1= (const float*)d_in[11];
    const float* b_edge1= (const float*)d_in[12];
    const float* w_lin2 = (const float*)d_in[13];
    const float* b_lin2 = (const float*)d_in[14];
    const float* w_ang  = (const float*)d_in[15];
    const float* b_ang  = (const float*)d_in[16];
    const float* w_ga1  = (const float*)d_in[17];
    const float* b_ga1  = (const float*)d_in[18];
    const float* w_ga2  = (const float*)d_in[19];
    const float* b_ga2  = (const float*)d_in[20];
    const int*   nlist  = (const int*)d_in[21];

    // ws layout (float units), R15 layout (proven):
    float* ws = (float*)d_ws;
    unsigned short* bt_ae  = (unsigned short*)(ws);
    unsigned short* bt_g2e = (unsigned short*)(ws + 4096);
    unsigned short* bt_sm  = (unsigned short*)(ws + 16384);
    unsigned short* bt_pij = (unsigned short*)(ws + 57344);
    float* P1a    = ws + 65536;
    float* E1     = ws + 131072;
    float* E2     = ws + 229376;
    unsigned short* P_i = (unsigned short*)(ws + 352256);
    unsigned short* P_j = (unsigned short*)(ws + 1007616);
    float* g1self = ws + 1662976;
    float* term4  = ws + 1728512;
    float* yga2   = ws + 1794048;
    float* acc3   = ws + 2449408;
    float* acc5   = ws + 2514944;
    float* g2acc  = ws + 2580480;
    unsigned short* P_jT = (unsigned short*)(ws + 3235840);  // 655360 ushorts
    if (ws_size < (size_t)3563520 * sizeof(float)) return;

    float* out = (float*)d_out;
    float* out_g1 = out;                 // 65536
    float* out_g2 = out + 65536;         // 3145728
    float* out_h2 = out + 3211264;       // 147456
    float* out_an = out + 3358720;       // 13107200

    hipMemsetAsync(acc3, 0, (65536 + 65536 + 655360) * sizeof(float), stream);

    prep_bt2<<<512, 256, 0, stream>>>(w_ang, w_ga1, w_edge1, w_lin2, w_proj, w_self,
                                      bt_ae, bt_g2e, bt_sm, bt_pij);
    gemm_small<<<dim3(5, 5), 256, 0, stream>>>(g1_ext, bt_sm, b_self, P1a, g1self, E1, E2);
    gemm_pij<<<dim3(80, 2), 256, 0, stream>>>(g2, bt_pij, P_i, P_j, P_jT);
    // ga1 first: unblocks k_f2 -> edge chain; anew (pure output) goes later
    k_ga1<<<1600, 256, 0, stream>>>(ae, bt_ae, P1a, P_i, P_jT, a_sw, b_ga1, g2acc);
    k_f2<<<512, 256, 0, stream>>>(g2acc, w_ga2, b_ga2, yga2);
    k_sym<<<512, 256, 0, stream>>>(g1_ext, g2, h2, sw, nlist, w_lin1, b_lin1, term4);
    edge_main<<<dim3(384, 3), 256, 0, stream>>>(g1_ext, g2, sw, nlist, bt_g2e, E1, E2,
                                                b_edge1, b_lin2, b_ga2, yga2,
                                                acc3, acc5, out_g2);
    k_anew<<<1600, 256, 0, stream>>>(ae, bt_ae, P1a, P_i, P_j, b_ang, out_an);
    k_f1<<<256, 256, 0, stream>>>(g1_ext, g1self, acc3, term4, acc5, h2, out_g1, out_h2);
}

// Round 18
// 166.021 us; speedup vs baseline: 1.1449x; 1.1449x over previous
//
#include <hip/hip_runtime.h>
#include <hip/hip_bf16.h>

// Problem constants
#define NLOC 512
#define NALL 640
#define NNEI 96
#define ASEL 20
#define NDIM 128
#define EDIM 64
#define ADIM 64

typedef short bf16x8 __attribute__((ext_vector_type(8)));
typedef float f32x4 __attribute__((ext_vector_type(4)));
typedef unsigned short ushort8 __attribute__((ext_vector_type(8)));
typedef unsigned short ushort4_t __attribute__((ext_vector_type(4)));

__device__ __forceinline__ unsigned short f2bf(float f) {
    unsigned int u = __float_as_uint(f);
    unsigned int r = (u + 0x7FFFu + ((u >> 16) & 1u)) >> 16;
    return (unsigned short)r;
}
__device__ __forceinline__ float bf2f(unsigned short u) {
    return __uint_as_float(((unsigned int)u) << 16);
}
__device__ __forceinline__ float silu(float x) { return x / (1.0f + __expf(-x)); }

__device__ __forceinline__ void cvt8_store(unsigned short* dst, const float* src) {
    float4 f0 = *(const float4*)src;
    float4 f1 = *(const float4*)(src + 4);
    ushort8 v;
    v[0] = f2bf(f0.x); v[1] = f2bf(f0.y); v[2] = f2bf(f0.z); v[3] = f2bf(f0.w);
    v[4] = f2bf(f1.x); v[5] = f2bf(f1.y); v[6] = f2bf(f1.z); v[7] = f2bf(f1.w);
    *(ushort8*)dst = v;
}

// butterfly sum over the 16-lane group (masks 1,2,4,8 stay inside the group)
__device__ __forceinline__ f32x4 red16(f32x4 v) {
#pragma unroll
    for (int m = 1; m < 16; m <<= 1) {
        v[0] += __shfl_xor(v[0], m);
        v[1] += __shfl_xor(v[1], m);
        v[2] += __shfl_xor(v[2], m);
        v[3] += __shfl_xor(v[3], m);
    }
    return v;
}

// ---------------- prep: ALL bf16 N-major weight blocks ----------------
__global__ void prep_bt2(const float* __restrict__ w_ang, const float* __restrict__ w_ga1,
                         const float* __restrict__ w_edge1, const float* __restrict__ w_lin2,
                         const float* __restrict__ w_proj, const float* __restrict__ w_self,
                         unsigned short* __restrict__ bt_ae, unsigned short* __restrict__ bt_g2e,
                         unsigned short* __restrict__ bt_sm, unsigned short* __restrict__ bt_pij) {
    int idx = blockIdx.x * 256 + threadIdx.x;  // 131072 total
    if (idx < 8192) {
        int k = idx & 63, n = idx >> 6;
        bt_ae[idx] = f2bf((n < 64) ? w_ang[k * 64 + n] : w_ga1[k * 64 + (n - 64)]);
    } else if (idx < 32768) {
        int id2 = idx - 8192;
        int k = id2 & 63, n = id2 >> 6;
        float v;
        if (n < 128)      v = w_edge1[(256 + k) * 128 + n];
        else if (n < 192) v = w_lin2[(256 + k) * 64 + (n - 128)];
        else if (n < 256) v = 0.0f;
        else              v = w_proj[k * 128 + (n - 256)];
        bt_g2e[id2] = f2bf(v);
    } else if (idx < 114688) {
        int id3 = idx - 32768;
        int k = id3 & 127, n = id3 >> 7;
        float v;
        if (n < 128)      v = w_edge1[k * 128 + n];
        else if (n < 192) v = w_lin2[k * 64 + (n - 128)];
        else if (n < 320) v = w_edge1[(128 + k) * 128 + (n - 192)];
        else if (n < 384) v = w_lin2[(128 + k) * 64 + (n - 320)];
        else if (n < 512) { int c = n - 384;
            v = (c < 64) ? w_ang[(64 + k) * 64 + c] : w_ga1[(64 + k) * 64 + (c - 64)]; }
        else              v = w_self[k * 128 + (n - 512)];
        bt_sm[id3] = f2bf(v);
    } else {
        int id4 = idx - 114688;  // < 16384
        int k = id4 & 63, n = id4 >> 6;
        float v;
        if (n < 128) v = (n < 64) ? w_ang[(192 + k) * 64 + n] : w_ga1[(192 + k) * 64 + (n - 64)];
        else { int c = n - 128;
            v = (c < 64) ? w_ang[(256 + k) * 64 + c] : w_ga1[(256 + k) * 64 + (c - 64)]; }
        bt_pij[id4] = f2bf(v);
    }
}

// ---------------- gemm_small: M=640 (g1_ext), K=128, N=640 (E1|E2|P1a|g1self) ----------
__global__ __launch_bounds__(256) void gemm_small(
    const float* __restrict__ g1_ext, const unsigned short* __restrict__ bt_sm,
    const float* __restrict__ b_self, float* __restrict__ P1a, float* __restrict__ g1self,
    float* __restrict__ E1, float* __restrict__ E2) {
    const int m0 = blockIdx.x * 128;
    const int ntile = blockIdx.y;  // 0..4
    __shared__ __align__(16) unsigned short Asl[128 * 136];
    __shared__ __align__(16) unsigned short Bsl[128 * 136];
    const int tid = threadIdx.x;
#pragma unroll
    for (int u = 0; u < 8; u++) {
        int g = tid + u * 256;
        int row = g >> 4, seg = g & 15;
        cvt8_store(&Asl[row * 136 + seg * 8], g1_ext + (m0 + row) * 128 + seg * 8);
        *(ushort8*)&Bsl[row * 136 + seg * 8] =
            *(const ushort8*)&bt_sm[(ntile * 128 + row) * 128 + seg * 8];
    }
    __syncthreads();
    const int lane = tid & 63, wid = tid >> 6;
    const int wr = wid >> 1, wc = wid & 1;
    const int r15 = lane & 15, kg = lane >> 4;
    f32x4 acc[4][4] = {};
#pragma unroll
    for (int h = 0; h < 4; h++) {
        bf16x8 afr[4], bfr[4];
#pragma unroll
        for (int mi = 0; mi < 4; mi++)
            afr[mi] = *(const bf16x8*)&Asl[(wr * 64 + mi * 16 + r15) * 136 + h * 32 + kg * 8];
#pragma unroll
        for (int ni = 0; ni < 4; ni++)
            bfr[ni] = *(const bf16x8*)&Bsl[(wc * 64 + ni * 16 + r15) * 136 + h * 32 + kg * 8];
#pragma unroll
        for (int mi = 0; mi < 4; mi++)
#pragma unroll
            for (int ni = 0; ni < 4; ni++)
                acc[mi][ni] = __builtin_amdgcn_mfma_f32_16x16x32_bf16(afr[mi], bfr[ni], acc[mi][ni], 0, 0, 0);
    }
#pragma unroll
    for (int mi = 0; mi < 4; mi++) {
        int rbase = m0 + wr * 64 + mi * 16 + kg * 4;
#pragma unroll
        for (int ni = 0; ni < 4; ni++) {
            int gc = ntile * 128 + wc * 64 + ni * 16 + r15;
#pragma unroll
            for (int t2 = 0; t2 < 4; t2++) {
                int a = rbase + t2;
                float z = acc[mi][ni][t2];
                if (gc < 192) { if (a < 512) E1[a * 192 + gc] = z; }
                else if (gc < 384) E2[a * 192 + (gc - 192)] = z;
                else if (gc < 512) { if (a < 512) P1a[a * 128 + (gc - 384)] = z; }
                else { if (a < 512) g1self[a * 128 + (gc - 512)] = silu(z + b_self[gc - 512]); }
            }
        }
    }
}

// ---------------- gemm_pij: M=10240 (l,i), K=64 (g2a), N=2x128 (P_i, P_j [+P_jT]) ------
__global__ __launch_bounds__(256) void gemm_pij(
    const float* __restrict__ g2, const unsigned short* __restrict__ bt_pij,
    unsigned short* __restrict__ P_i, unsigned short* __restrict__ P_j,
    unsigned short* __restrict__ P_jT) {
    const int m0 = blockIdx.x * 128;
    const int ntile = blockIdx.y;  // 0 = P_i, 1 = P_j
    __shared__ __align__(16) unsigned short Asl[128 * 72];
    const int tid = threadIdx.x;
#pragma unroll
    for (int u = 0; u < 4; u++) {
        int g = tid + u * 256;
        int row = g >> 3, seg = g & 7;
        int li = m0 + row, l = li / 20, i = li - l * 20;
        cvt8_store(&Asl[row * 72 + seg * 8], g2 + (l * 96 + i) * 64 + seg * 8);
    }
    __syncthreads();
    const int lane = tid & 63, wid = tid >> 6;
    const int wr = wid >> 1, wc = wid & 1;
    const int r15 = lane & 15, kg = lane >> 4;
    f32x4 acc[4][4] = {};
#pragma unroll
    for (int h = 0; h < 2; h++) {
        bf16x8 afr[4], bfr[4];
#pragma unroll
        for (int mi = 0; mi < 4; mi++)
            afr[mi] = *(const bf16x8*)&Asl[(wr * 64 + mi * 16 + r15) * 72 + h * 32 + kg * 8];
#pragma unroll
        for (int ni = 0; ni < 4; ni++)
            bfr[ni] = *(const bf16x8*)&bt_pij[(ntile * 128 + wc * 64 + ni * 16 + r15) * 64 + h * 32 + kg * 8];
#pragma unroll
        for (int mi = 0; mi < 4; mi++)
#pragma unroll
            for (int ni = 0; ni < 4; ni++)
                acc[mi][ni] = __builtin_amdgcn_mfma_f32_16x16x32_bf16(afr[mi], bfr[ni], acc[mi][ni], 0, 0, 0);
    }
    unsigned short* Pout = (ntile == 0) ? P_i : P_j;
#pragma unroll
    for (int mi = 0; mi < 4; mi++) {
        int rbase = m0 + wr * 64 + mi * 16 + kg * 4;
#pragma unroll
        for (int ni = 0; ni < 4; ni++) {
            int c = wc * 64 + ni * 16 + r15;
#pragma unroll
            for (int t2 = 0; t2 < 4; t2++) {
                unsigned short v = f2bf(acc[mi][ni][t2]);
                int li = rbase + t2;
                Pout[li * 128 + c] = v;
                if (ntile == 1) {
                    int l = li / 20, j = li - l * 20;
                    P_jT[(l * 128 + c) * 20 + j] = v;
                }
            }
        }
    }
}

// ---------------- sym op + term4 = silu(sym @ w_lin1 + b_lin1) ----------------
__global__ void k_sym(const float* __restrict__ g1_ext, const float* __restrict__ g2,
                      const float* __restrict__ h2, const float* __restrict__ sw,
                      const int* __restrict__ nlist, const float* __restrict__ w_lin1,
                      const float* __restrict__ b_lin1, float* __restrict__ term4) {
    int l = blockIdx.x, t = threadIdx.x;  // 256 threads
    __shared__ float h2s[96 * 3];
    __shared__ float sws[96];
    __shared__ int nls[96];
    __shared__ float hg[3 * 192];
    __shared__ float symv[768];
    __shared__ float red[128];
    if (t < 96) { sws[t] = sw[l * 96 + t]; nls[t] = nlist[l * 96 + t]; }
    for (int p = t; p < 288; p += 256) h2s[p] = h2[l * 288 + p];
    __syncthreads();
    const float inv = 0.1020620726f;
    for (int p = t; p < 576; p += 256) {
        float acc = 0.0f;
        if (p < 192) {
            int tt = p >> 6, d = p & 63;
            for (int n = 0; n < 96; n++)
                acc += h2s[n * 3 + tt] * g2[(l * 96 + n) * 64 + d] * sws[n];
            hg[tt * 192 + d] = acc * inv;
        } else {
            int q = p - 192;
            int tt = q >> 7, d = q & 127;
            for (int n = 0; n < 96; n++)
                acc += h2s[n * 3 + tt] * g1_ext[nls[n] * 128 + d] * sws[n];
            hg[tt * 192 + 64 + d] = acc * inv;
        }
    }
    __syncthreads();
    for (int p = t; p < 768; p += 256) {
        float acc = 0.0f;
        if (p < 256) {
            int d = p >> 2, a = p & 3;
            for (int tt = 0; tt < 3; tt++) acc += hg[tt * 192 + d] * hg[tt * 192 + a];
        } else {
            int q = p - 256;
            int d = q >> 2, a = q & 3;
            for (int tt = 0; tt < 3; tt++) acc += hg[tt * 192 + 64 + d] * hg[tt * 192 + 64 + a];
        }
        symv[p] = acc;
    }
    __syncthreads();
    {
        int col = t & 127, half = t >> 7;
        float acc = 0.0f;
        int k0 = half * 384;
#pragma unroll 8
        for (int k = k0; k < k0 + 384; k++) acc += symv[k] * w_lin1[k * 128 + col];
        if (half) red[col] = acc;
        __syncthreads();
        if (!half) term4[l * 128 + col] = silu(acc + red[col] + b_lin1[col]);
    }
}

// ---------------- angle main GEMM (R16 fused uniform-wave version, proven 58us) --------
__global__ __launch_bounds__(256) void angle_main(
    const float* __restrict__ ae, const unsigned short* __restrict__ bt_ae,
    const float* __restrict__ P1a, const unsigned short* __restrict__ P_i,
    const unsigned short* __restrict__ P_j, const unsigned short* __restrict__ P_jT,
    const float* __restrict__ a_sw,
    const float* __restrict__ b_ang, const float* __restrict__ b_ga1,
    float* __restrict__ g2acc, float* __restrict__ a_new_out) {
    const int m0 = blockIdx.x * 128;
    __shared__ __align__(16) unsigned short Asl[128 * 72];
    const int tid = threadIdx.x;
#pragma unroll
    for (int u = 0; u < 4; u++) {
        int g = tid + u * 256;
        int row = g >> 3, seg = g & 7;
        cvt8_store(&Asl[row * 72 + seg * 8], ae + (m0 + row) * 64 + seg * 8);
    }
    __syncthreads();
    const int lane = tid & 63, wid = tid >> 6;
    const int r15 = lane & 15, kg = lane >> 4;
    f32x4 accA[2][4] = {};
    f32x4 accB[2][4] = {};
#pragma unroll
    for (int h = 0; h < 2; h++) {
        bf16x8 afr[2], bfrA[4], bfrB[4];
#pragma unroll
        for (int mi = 0; mi < 2; mi++)
            afr[mi] = *(const bf16x8*)&Asl[(wid * 32 + mi * 16 + r15) * 72 + h * 32 + kg * 8];
#pragma unroll
        for (int ni = 0; ni < 4; ni++) {
            bfrA[ni] = *(const bf16x8*)&bt_ae[(ni * 16 + r15) * 64 + h * 32 + kg * 8];
            bfrB[ni] = *(const bf16x8*)&bt_ae[(64 + ni * 16 + r15) * 64 + h * 32 + kg * 8];
        }
#pragma unroll
        for (int mi = 0; mi < 2; mi++)
#pragma unroll
            for (int ni = 0; ni < 4; ni++) {
                accA[mi][ni] = __builtin_amdgcn_mfma_f32_16x16x32_bf16(bfrA[ni], afr[mi], accA[mi][ni], 0, 0, 0);
                accB[mi][ni] = __builtin_amdgcn_mfma_f32_16x16x32_bf16(afr[mi], bfrB[ni], accB[mi][ni], 0, 0, 0);
            }
    }
    // ---- epilogue A: a_new, per-lane row fixed, cols vectorized ----
#pragma unroll
    for (int mi = 0; mi < 2; mi++) {
        int r = m0 + wid * 32 + mi * 16 + r15;
        int l = r / 400;
        int rem = r - l * 400;
        int i = rem / 20;
        int j = rem - i * 20;
        const float* p1b = P1a + l * 128;
        const unsigned short* pib = P_i + (l * 20 + i) * 128;
        const unsigned short* pjb = P_j + (l * 20 + j) * 128;
        int lr = r - m0;
#pragma unroll
        for (int ni = 0; ni < 4; ni++) {
            int n0 = ni * 16 + kg * 4;
            f32x4 p1v = *(const f32x4*)&p1b[n0];
            ushort4_t piv = *(const ushort4_t*)&pib[n0];
            ushort4_t pjv = *(const ushort4_t*)&pjb[n0];
            ushort4_t aev = *(const ushort4_t*)&Asl[lr * 72 + n0];
            f32x4 bbv = *(const f32x4*)&b_ang[n0];
            f32x4 outv;
#pragma unroll
            for (int t2 = 0; t2 < 4; t2++) {
                float z = accA[mi][ni][t2] + p1v[t2] + bf2f(piv[t2]) + bf2f(pjv[t2]);
                outv[t2] = (bf2f(aev[t2]) + silu(z + bbv[t2])) * 0.70710678f;
            }
            *(f32x4*)&a_new_out[r * 64 + n0] = outv;
        }
    }
    // ---- epilogue B: ga1 atomics, P_jT vectorized over j ----
#pragma unroll
    for (int mi = 0; mi < 2; mi++) {
        int rbase = m0 + wid * 32 + mi * 16 + kg * 4;
        int l = rbase / 400;
        int rem = rbase - l * 400;
        int i = rem / 20;
        int j0 = rem - i * 20;
        const float* p1b = P1a + l * 128;
        const unsigned short* pib = P_i + (l * 20 + i) * 128;
        float swi = a_sw[l * 20 + i];
        f32x4 swjv = *(const f32x4*)&a_sw[l * 20 + j0];
#pragma unroll
        for (int ni = 0; ni < 4; ni++) {
            int c = 64 + ni * 16 + r15;
            int cc = c - 64;
            float base = p1b[c] + bf2f(pib[c]);
            float bb = b_ga1[cc];
            ushort4_t pjtv = *(const ushort4_t*)&P_jT[(l * 128 + c) * 20 + j0];
            float part = 0.0f;
#pragma unroll
            for (int t2 = 0; t2 < 4; t2++) {
                float z = accB[mi][ni][t2] + base + bf2f(pjtv[t2]);
                part += silu(swi * swjv[t2] * z + bb);
            }
            atomicAdd(&g2acc[(l * 20 + i) * 64 + cc], part);
        }
    }
}

// ---------------- F2: yga2 = silu((g2acc/20) @ w_ga2 + b_ga2) ----------------
__global__ void k_f2(const float* __restrict__ g2ang_acc, const float* __restrict__ w_ga2,
                     const float* __restrict__ b_ga2, float* __restrict__ yga2) {
    int l = blockIdx.x, t = threadIdx.x;
    __shared__ float gs[20 * 64];
    for (int p = t; p < 1280; p += 256) gs[p] = g2ang_acc[l * 1280 + p] * 0.05f;
    __syncthreads();
    for (int p = t; p < 1280; p += 256) {
        int i = p >> 6, c = p & 63;
        float acc = b_ga2[c];
#pragma unroll 8
        for (int k = 0; k < 64; k++) acc += gs[i * 64 + k] * w_ga2[k * 64 + c];
        yga2[l * 1280 + p] = silu(acc);
    }
}

// ---------------- edge main GEMM: all tiles uniform-wave swapped layout ----------
// ntile 0 (edge1->acc5) & 2 (proj->acc3): per-lane row fixed -> E2/g1_ext gathers become
// f32x4 loads; row-sum via 16-lane shfl butterfly; 1 lane issues atomics (16x fewer).
__global__ __launch_bounds__(256) void edge_main(
    const float* __restrict__ g1_ext, const float* __restrict__ g2, const float* __restrict__ sw,
    const int* __restrict__ nlist, const unsigned short* __restrict__ bt_g2e,
    const float* __restrict__ E1, const float* __restrict__ E2,
    const float* __restrict__ b_edge1, const float* __restrict__ b_lin2,
    const float* __restrict__ b_ga2, const float* __restrict__ yga2,
    float* __restrict__ g1_acc3, float* __restrict__ g1_acc5, float* __restrict__ g2_new_out) {
    const int m0 = blockIdx.x * 128;
    const int ntile = blockIdx.y;
    __shared__ __align__(16) unsigned short Asl[128 * 72];
    const int tid = threadIdx.x;
#pragma unroll
    for (int u = 0; u < 4; u++) {
        int g = tid + u * 256;
        int row = g >> 3, seg = g & 7;
        cvt8_store(&Asl[row * 72 + seg * 8], g2 + (m0 + row) * 64 + seg * 8);
    }
    __syncthreads();
    const int lane = tid & 63, wid = tid >> 6;
    const int r15 = lane & 15, kg = lane >> 4;
    if (ntile == 1) {
        f32x4 acc[2][4] = {};
#pragma unroll
        for (int h = 0; h < 2; h++) {
            bf16x8 afr[2], bfr[4];
#pragma unroll
            for (int mi = 0; mi < 2; mi++)
                afr[mi] = *(const bf16x8*)&Asl[(wid * 32 + mi * 16 + r15) * 72 + h * 32 + kg * 8];
#pragma unroll
            for (int ni = 0; ni < 4; ni++)
                bfr[ni] = *(const bf16x8*)&bt_g2e[(128 + ni * 16 + r15) * 64 + h * 32 + kg * 8];
#pragma unroll
            for (int mi = 0; mi < 2; mi++)
#pragma unroll
                for (int ni = 0; ni < 4; ni++)
                    acc[mi][ni] = __builtin_amdgcn_mfma_f32_16x16x32_bf16(bfr[ni], afr[mi], acc[mi][ni], 0, 0, 0);
        }
#pragma unroll
        for (int mi = 0; mi < 2; mi++) {
            int r = m0 + wid * 32 + mi * 16 + r15;
            int l = r / 96;
            int nn = r - l * 96;
            const float* e1 = E1 + l * 192 + 128;
            const float* e2 = E2 + nlist[r] * 192 + 128;
            bool hasyg = (nn < ASEL);
            const float* yg = yga2 + (l * 20 + nn) * 64;
            int lr = r - m0;
#pragma unroll
            for (int ni = 0; ni < 4; ni++) {
                int n0 = ni * 16 + kg * 4;
                f32x4 e1v = *(const f32x4*)&e1[n0];
                f32x4 e2v = *(const f32x4*)&e2[n0];
                f32x4 bbv = *(const f32x4*)&b_lin2[n0];
                f32x4 bg2 = *(const f32x4*)&b_ga2[n0];
                ushort4_t g2v = *(const ushort4_t*)&Asl[lr * 72 + n0];
                f32x4 outv;
#pragma unroll
                for (int t2 = 0; t2 < 4; t2++) {
                    float z = acc[mi][ni][t2] + e1v[t2] + e2v[t2];
                    float y = silu(z + bbv[t2]);
                    float ygv = hasyg ? yg[n0 + t2] : silu(bg2[t2]);
                    outv[t2] = (bf2f(g2v[t2]) + y + ygv) * 0.57735027f;
                }
                *(f32x4*)&g2_new_out[r * 64 + n0] = outv;
            }
        }
    } else {
        // ntile 0 (edge1, cols 0..127) or 2 (proj, cols 0..127): swapped, acc[2][8]
        const int bn = (ntile == 0) ? 0 : 256;
        f32x4 acc[2][8] = {};
#pragma unroll
        for (int h = 0; h < 2; h++) {
            bf16x8 afr[2], bfr[8];
#pragma unroll
            for (int mi = 0; mi < 2; mi++)
                afr[mi] = *(const bf16x8*)&Asl[(wid * 32 + mi * 16 + r15) * 72 + h * 32 + kg * 8];
#pragma unroll
            for (int ni = 0; ni < 8; ni++)
                bfr[ni] = *(const bf16x8*)&bt_g2e[(bn + ni * 16 + r15) * 64 + h * 32 + kg * 8];
#pragma unroll
            for (int mi = 0; mi < 2; mi++)
#pragma unroll
                for (int ni = 0; ni < 8; ni++)
                    acc[mi][ni] = __builtin_amdgcn_mfma_f32_16x16x32_bf16(bfr[ni], afr[mi], acc[mi][ni], 0, 0, 0);
        }
#pragma unroll
        for (int mi = 0; mi < 2; mi++) {
            int r = m0 + wid * 32 + mi * 16 + r15;  // 16-aligned block => same l for all r15
            int l = r / 96;
            float swr = sw[r];
            int nr = nlist[r];
            if (ntile == 0) {
                const float* e1 = E1 + l * 192;
                const float* e2 = E2 + nr * 192;
#pragma unroll
                for (int ni = 0; ni < 8; ni++) {
                    int n0 = ni * 16 + kg * 4;
                    f32x4 e1v = *(const f32x4*)&e1[n0];
                    f32x4 e2v = *(const f32x4*)&e2[n0];
                    f32x4 bbv = *(const f32x4*)&b_edge1[n0];
                    f32x4 p;
#pragma unroll
                    for (int t2 = 0; t2 < 4; t2++)
                        p[t2] = silu(acc[mi][ni][t2] + e1v[t2] + e2v[t2] + bbv[t2]) * swr;
                    p = red16(p);
                    if (r15 == 0) {
#pragma unroll
                        for (int t2 = 0; t2 < 4; t2++)
                            atomicAdd(&g1_acc5[l * 128 + n0 + t2], p[t2]);
                    }
                }
            } else {
                const float* gv = g1_ext + nr * 128;
#pragma unroll
                for (int ni = 0; ni < 8; ni++) {
                    int n0 = ni * 16 + kg * 4;
                    f32x4 g4 = *(const f32x4*)&gv[n0];
                    f32x4 p;
#pragma unroll
                    for (int t2 = 0; t2 < 4; t2++)
                        p[t2] = acc[mi][ni][t2] * g4[t2] * swr;
                    p = red16(p);
                    if (r15 == 0) {
#pragma unroll
                        for (int t2 = 0; t2 < 4; t2++)
                            atomicAdd(&g1_acc3[l * 128 + n0 + t2], p[t2]);
                    }
                }
            }
        }
    }
}

// ---------------- F1: g1_new + h2 passthrough ----------------
__global__ void k_f1(const float* __restrict__ g1_ext, const float* __restrict__ g1self,
                     const float* __restrict__ acc3, const float* __restrict__ term4,
                     const float* __restrict__ acc5, const float* __restrict__ h2,
                     float* __restrict__ out_g1, float* __restrict__ out_h2) {
    int idx = blockIdx.x * 256 + threadIdx.x;  // 65536
    float v = g1_ext[idx] + g1self[idx] + acc3[idx] * (1.0f / 96.0f) + term4[idx] +
              acc5[idx] * (1.0f / 96.0f);
    out_g1[idx] = v * 0.4472135955f;
    if (idx < 36864)
        *(float4*)&out_h2[idx * 4] = *(const float4*)&h2[idx * 4];
}

extern "C" void kernel_launch(void* const* d_in, const int* in_sizes, int n_in,
                              void* d_out, int out_size, void* d_ws, size_t ws_size,
                              hipStream_t stream) {
    if (n_in < 22 || in_sizes[0] != 81920 || in_sizes[3] != 13107200) return;
    const float* g1_ext = (const float*)d_in[0];
    const float* g2     = (const float*)d_in[1];
    const float* h2     = (const float*)d_in[2];
    const float* ae     = (const float*)d_in[3];
    const float* sw     = (const float*)d_in[4];
    const float* a_sw   = (const float*)d_in[5];
    const float* w_self = (const float*)d_in[6];
    const float* b_self = (const float*)d_in[7];
    const float* w_proj = (const float*)d_in[8];
    const float* w_lin1 = (const float*)d_in[9];
    const float* b_lin1 = (const float*)d_in[10];
    const float* w_edge1= (const float*)d_in[11];
    const float* b_edge1= (const float*)d_in[12];
    const float* w_lin2 = (const float*)d_in[13];
    const float* b_lin2 = (const float*)d_in[14];
    const float* w_ang  = (const float*)d_in[15];
    const float* b_ang  = (const float*)d_in[16];
    const float* w_ga1  = (const float*)d_in[17];
    const float* b_ga1  = (const float*)d_in[18];
    const float* w_ga2  = (const float*)d_in[19];
    const float* b_ga2  = (const float*)d_in[20];
    const int*   nlist  = (const int*)d_in[21];

    // ws layout (float units), R15/R16 layout (proven):
    float* ws = (float*)d_ws;
    unsigned short* bt_ae  = (unsigned short*)(ws);
    unsigned short* bt_g2e = (unsigned short*)(ws + 4096);
    unsigned short* bt_sm  = (unsigned short*)(ws + 16384);
    unsigned short* bt_pij = (unsigned short*)(ws + 57344);
    float* P1a    = ws + 65536;
    float* E1     = ws + 131072;
    float* E2     = ws + 229376;
    unsigned short* P_i = (unsigned short*)(ws + 352256);
    unsigned short* P_j = (unsigned short*)(ws + 1007616);
    float* g1self = ws + 1662976;
    float* term4  = ws + 1728512;
    float* yga2   = ws + 1794048;
    float* acc3   = ws + 2449408;
    float* acc5   = ws + 2514944;
    float* g2acc  = ws + 2580480;
    unsigned short* P_jT = (unsigned short*)(ws + 3235840);  // 655360 ushorts
    if (ws_size < (size_t)3563520 * sizeof(float)) return;

    float* out = (float*)d_out;
    float* out_g1 = out;                 // 65536
    float* out_g2 = out + 65536;         // 3145728
    float* out_h2 = out + 3211264;       // 147456
    float* out_an = out + 3358720;       // 13107200

    hipMemsetAsync(acc3, 0, (65536 + 65536 + 655360) * sizeof(float), stream);

    prep_bt2<<<512, 256, 0, stream>>>(w_ang, w_ga1, w_edge1, w_lin2, w_proj, w_self,
                                      bt_ae, bt_g2e, bt_sm, bt_pij);
    gemm_small<<<dim3(5, 5), 256, 0, stream>>>(g1_ext, bt_sm, b_self, P1a, g1self, E1, E2);
    gemm_pij<<<dim3(80, 2), 256, 0, stream>>>(g2, bt_pij, P_i, P_j, P_jT);
    k_sym<<<512, 256, 0, stream>>>(g1_ext, g2, h2, sw, nlist, w_lin1, b_lin1, term4);
    angle_main<<<1600, 256, 0, stream>>>(ae, bt_ae, P1a, P_i, P_j, P_jT, a_sw, b_ang, b_ga1,
                                         g2acc, out_an);
    k_f2<<<512, 256, 0, stream>>>(g2acc, w_ga2, b_ga2, yga2);
    edge_main<<<dim3(384, 3), 256, 0, stream>>>(g1_ext, g2, sw, nlist, bt_g2e, E1, E2,
                                                b_edge1, b_lin2, b_ga2, yga2,
                                                acc3, acc5, out_g2);
    k_f1<<<256, 256, 0, stream>>>(g1_ext, g1self, acc3, term4, acc5, h2, out_g1, out_h2);
}